// Round 23
// baseline (195.505 us; speedup 1.0000x reference)
//
#include <hip/hip_runtime.h>
#include <hip/hip_bf16.h>

#define DD 256
#define KK 4
#define CSZ 1024
#define NROWS 16384
#define TM 32           // rows per block -> 512 blocks, 2 per CU (LDS ~52 KB)
#define NTHR 512        // 8 waves: each = both row-tiles x one 8-tile segment
#define TAU 0.5f
#define MAXC 128

typedef __attribute__((ext_vector_type(8))) short bf16x8;
typedef __attribute__((ext_vector_type(4))) float f32x4;

__device__ __forceinline__ short f2bf(float f) {
    __hip_bfloat16 h = __float2bfloat16(f);
    return (short)__builtin_bit_cast(unsigned short, h);
}
__device__ __forceinline__ float bf2f(short s) {
    unsigned u = ((unsigned)(unsigned short)s) << 16;
    return __builtin_bit_cast(float, u);
}
__device__ __forceinline__ unsigned long long enc_d(double d) {
    unsigned long long u = __double_as_longlong(d);
    return (u & 0x8000000000000000ull) ? ~u : (u | 0x8000000000000000ull);
}

// pack codebook into MFMA B-fragment order (one coalesced 1KB stream per load)
__global__ __launch_bounds__(256) void cb_pack(const float* __restrict__ cb,
                                               short* __restrict__ packed) {
    int idx  = blockIdx.x * 256 + threadIdx.x;       // over 4*64*8*64 = 131072
    int lane = idx & 63;
    int kk   = (idx >> 6) & 7;
    int tg   = idx >> 9;                             // k*64 + tile
    int k    = tg >> 6;
    int ctg  = tg & 63;
    int c    = ctg * 16 + (lane & 15);
    int d0   = kk * 32 + (lane >> 4) * 8;
    const float* src = cb + ((size_t)(k * CSZ + c)) * DD + d0;
    short* dst = packed + (size_t)idx * 8;
#pragma unroll
    for (int j = 0; j < 8; ++j) dst[j] = f2bf(src[j]);
}

// per-entry squared norms, wave-per-entry (coalesced)
__global__ __launch_bounds__(256) void cnorm_kernel(const float* __restrict__ cb,
                                                    double* __restrict__ cn_d,
                                                    float* __restrict__ cn_f) {
    int wv = threadIdx.x >> 6, l = threadIdx.x & 63;
    int e = blockIdx.x * 4 + wv;                     // grid 1024 -> 4096 entries
    float4 v = *(const float4*)(cb + (size_t)e * DD + l * 4);
    double s = (double)v.x * (double)v.x + (double)v.y * (double)v.y
             + (double)v.z * (double)v.z + (double)v.w * (double)v.w;
#pragma unroll
    for (int off = 32; off > 0; off >>= 1) s += __shfl_xor(s, off, 64);
    if (l == 0) { cn_d[e] = s; cn_f[e] = (float)s; }
}

// coalesced fragment load from packed codebook; t_ is the GLOBAL tile id (0..63)
#define LOADB(Bv, CNv, t_) {                                          \
    const short* bp_ = pkk + (size_t)(t_) * 4096 + l * 8;             \
    _Pragma("unroll")                                                 \
    for (int kk = 0; kk < 8; ++kk)                                    \
        Bv[kk] = *(const bf16x8*)(bp_ + kk * 512);                    \
    CNv = cnfk[(t_) * 16 + l15]; }

// positive-key update; fmaxf clamp is load-bearing (stage-0 dist can be <0)
#define KUPD(rt_, dval) {                                             \
    float dc_ = fmaxf((dval), 0.f);                                   \
    unsigned kx_ = (__builtin_bit_cast(unsigned, dc_) & 0xFFFFFC00u)  \
                   | (unsigned)cE_;                                   \
    unsigned mx_ = (b0[rt_][reg] > kx_) ? b0[rt_][reg] : kx_;         \
    b0[rt_][reg] = (b0[rt_][reg] < kx_) ? b0[rt_][reg] : kx_;         \
    b1[rt_][reg] = (b1[rt_][reg] < mx_) ? b1[rt_][reg] : mx_; }

#define TILE2(Bv, CNv, t_) {                                          \
    f32x4 ac0 = {0.f,0.f,0.f,0.f}, ac1 = {0.f,0.f,0.f,0.f};           \
    _Pragma("unroll")                                                 \
    for (int kk = 0; kk < 8; ++kk) {                                  \
        ac0 = __builtin_amdgcn_mfma_f32_16x16x32_bf16(A[0][kk], Bv[kk], ac0, 0,0,0); \
        ac1 = __builtin_amdgcn_mfma_f32_16x16x32_bf16(A[1][kk], Bv[kk], ac1, 0,0,0); \
    }                                                                 \
    const int cE_ = (t_) * 16 + l15;                                  \
    _Pragma("unroll")                                                 \
    for (int reg = 0; reg < 4; ++reg) {                               \
        KUPD(0, fmaf(-2.f, ac0[reg], CNv));                           \
        KUPD(1, fmaf(-2.f, ac1[reg], CNv));                           \
    } }

__global__ __launch_bounds__(NTHR, 2) void rvq_kernel(const float* __restrict__ z,
                                                  const float* __restrict__ cb,
                                                  const short* __restrict__ packed,
                                                  const double* __restrict__ cn_d,
                                                  const float* __restrict__ cn_f,
                                                  float* __restrict__ out) {
    // double-compensated residual: fp32 hi + bf16 lo  (~32-bit mantissa)
    __shared__ __align__(16) float res_hi[TM][DD + 4];   // 33,280 B (16B-aligned rows)
    __shared__ short res_lo[TM][DD];                     // 16,384 B
    __shared__ unsigned wrowmin[8][TM];
    __shared__ int cand[MAXC];
    __shared__ unsigned long long rowkey[2][TM];
    __shared__ int ncand;

    const int tid = threadIdx.x;                     // 0..511
    const int l   = tid & 63;        // lane
    const int wv  = tid >> 6;        // wave 0..7
    const int l15 = l & 15;
    const int q   = l >> 4;          // quarter 0..3
    const int q8  = q * 8;
    const int row0 = blockIdx.x * TM;
    const int hrow = tid >> 8;       // 0/1: row split for 512-thread loops
    const int hd   = tid & 255;      // d index for 512-thread loops

    // ---- init: hi = z (exact), lo = 0; rowkey/ncand ----
#pragma unroll 4
    for (int it = 0; it < TM / 2; ++it) {
        int r = it * 2 + hrow;
        res_hi[r][hd] = z[(size_t)(row0 + r) * DD + hd];
        res_lo[r][hd] = 0;
    }
    if (tid < TM) { rowkey[0][tid] = ~0ull; rowkey[1][tid] = ~0ull; }
    if (tid == 0) ncand = 0;
    __syncthreads();

    for (int k = 0; k < KK; ++k) {
        const int kb = k & 1;
        // ---- A fragments for both row-tiles from res_hi (bf16 of hi) ----
        bf16x8 A[2][8];
#pragma unroll
        for (int rtl = 0; rtl < 2; ++rtl)
#pragma unroll
            for (int kk = 0; kk < 8; ++kk) {
                const float* rp = &res_hi[rtl * 16 + l15][kk * 32 + q8];
                float4 v0 = *(const float4*)rp;
                float4 v1 = *(const float4*)(rp + 4);
                bf16x8 a;
                a[0] = f2bf(v0.x); a[1] = f2bf(v0.y);
                a[2] = f2bf(v0.z); a[3] = f2bf(v0.w);
                a[4] = f2bf(v1.x); a[5] = f2bf(v1.y);
                a[6] = f2bf(v1.z); a[7] = f2bf(v1.w);
                A[rtl][kk] = a;
            }

        // ---- MFMA scan over this wave's 8 tiles (single-buffered; TLP hides) ----
        const short* __restrict__ pkk  = packed + (size_t)k * CSZ * DD;
        const float* __restrict__ cnfk = cn_f + k * CSZ;
        unsigned b0[2][4], b1[2][4];
#pragma unroll
        for (int rtl = 0; rtl < 2; ++rtl)
#pragma unroll
            for (int reg = 0; reg < 4; ++reg) { b0[rtl][reg] = ~0u; b1[rtl][reg] = ~0u; }

        {
            const int t0 = wv * 8;
            bf16x8 Bx[8];
            float cnX;
#pragma unroll 1
            for (int t = t0; t < t0 + 8; ++t) {
                LOADB(Bx, cnX, t);
                TILE2(Bx, cnX, t);
            }
        }

        // ---- per-wave row mins (16-lane groups) ----
#pragma unroll
        for (int rtl = 0; rtl < 2; ++rtl)
#pragma unroll
            for (int reg = 0; reg < 4; ++reg) {
                unsigned m = b0[rtl][reg];
                m = min(m, (unsigned)__shfl_xor((int)m, 1, 64));
                m = min(m, (unsigned)__shfl_xor((int)m, 2, 64));
                m = min(m, (unsigned)__shfl_xor((int)m, 4, 64));
                m = min(m, (unsigned)__shfl_xor((int)m, 8, 64));
                if (l15 == 0) wrowmin[wv][rtl * 16 + q * 4 + reg] = m;
            }
        __syncthreads();                                   // B1

        // ---- capture: block min over all 8 waves; best+2nd within TAU ----
#pragma unroll
        for (int rtl = 0; rtl < 2; ++rtl)
#pragma unroll
            for (int reg = 0; reg < 4; ++reg) {
                const int row = rtl * 16 + q * 4 + reg;
                unsigned rk = min(min(min(wrowmin[0][row], wrowmin[1][row]),
                                      min(wrowmin[2][row], wrowmin[3][row])),
                                  min(min(wrowmin[4][row], wrowmin[5][row]),
                                      min(wrowmin[6][row], wrowmin[7][row])));
                float thrf = __builtin_bit_cast(float, rk | 0x3FFu) + TAU;
                unsigned tkey = (__builtin_bit_cast(unsigned, thrf) & 0xFFFFFC00u) | 0x3FFu;
                if (b0[rtl][reg] <= tkey) {
                    int sl = atomicAdd(&ncand, 1);
                    if (sl < MAXC) cand[sl] = row | ((int)(b0[rtl][reg] & 0x3FFu) << 16);
                }
                if (b1[rtl][reg] <= tkey) {
                    int sl = atomicAdd(&ncand, 1);
                    if (sl < MAXC) cand[sl] = row | ((int)(b1[rtl][reg] & 0x3FFu) << 16);
                }
            }
        __syncthreads();                                   // B2

        // ---- fp64 refine on hi+lo reconstruction: 32 16-lane groups ----
        const int nc = (ncand < MAXC) ? ncand : MAXC;
        const float* __restrict__ cbk   = cb + (size_t)k * CSZ * DD;
        const double* __restrict__ cndk = cn_d + k * CSZ;
        const int g = tid >> 4;                            // group 0..31
        for (int i = g; i < nc; i += 32) {
            int rc  = cand[i];
            int row = rc & 0xFFFF;
            int c   = rc >> 16;
            const float* crow = cbk + (size_t)c * DD;
            double p = 0.0;
#pragma unroll
            for (int ii = 0; ii < 16; ++ii) {
                int d = ii * 16 + l15;
                double rv = (double)res_hi[row][d] + (double)bf2f(res_lo[row][d]);
                p += rv * (double)crow[d];
            }
            p += __shfl_xor(p, 1, 64);
            p += __shfl_xor(p, 2, 64);
            p += __shfl_xor(p, 4, 64);
            p += __shfl_xor(p, 8, 64);
            if (l15 == 0) {
                double dist = cndk[c] - 2.0 * p;
                unsigned long long key =
                    (enc_d(dist) & 0xFFFFFFFFFFFFFC00ull) | (unsigned long long)c;
                atomicMin(&rowkey[kb][row], key);
            }
        }
        __syncthreads();                                   // B3

        // ---- idx write (direct, f32) + residual update + resets ----
        if (tid < TM)
            out[(size_t)NROWS * DD + (size_t)(row0 + tid) * KK + k] =
                (float)(int)(rowkey[kb][tid] & 1023ull);
#pragma unroll 4
        for (int it = 0; it < TM / 2; ++it) {
            int r = it * 2 + hrow;
            int c = (int)(rowkey[kb][r] & 1023ull);        // broadcast LDS read
            double qv = (double)cbk[(size_t)c * DD + hd];
            double rd = (double)res_hi[r][hd] + (double)bf2f(res_lo[r][hd]);
            double s  = qv - rd;       // stop_gradient(q - residual)
            double zq = rd + s;        // z_q value
            double rn = rd - zq;       // next residual
            float hi = (float)rn;
            res_hi[r][hd] = hi;
            res_lo[r][hd] = f2bf((float)(rn - (double)hi));
        }
        if (tid < TM) rowkey[kb ^ 1][tid] = ~0ull;
        if (tid == 0) ncand = 0;
        __syncthreads();                                   // B4
    }

    // ---- z_q_final = z - residual_final (f32 out, chunk 0) ----
#pragma unroll 4
    for (int it = 0; it < TM / 2; ++it) {
        int r = it * 2 + hrow;
        size_t o = (size_t)(row0 + r) * DD + hd;
        double rv = (double)res_hi[r][hd] + (double)bf2f(res_lo[r][hd]);
        out[o] = (float)((double)z[o] - rv);
    }
}

extern "C" void kernel_launch(void* const* d_in, const int* in_sizes, int n_in,
                              void* d_out, int out_size, void* d_ws, size_t ws_size,
                              hipStream_t stream) {
    (void)in_sizes; (void)n_in; (void)out_size; (void)ws_size;
    const float* z  = (const float*)d_in[0];
    const float* cb = (const float*)d_in[1];

    char* ws = (char*)d_ws;
    short*  packed = (short*)ws;                                  // 2 MB
    double* cn_d  = (double*)(ws + (size_t)2 * 1024 * 1024);      // 32 KB
    float*  cn_f  = (float*)(ws + (size_t)2 * 1024 * 1024 + 32 * 1024);  // 16 KB
    float* out = (float*)d_out;

    cb_pack<<<(KK * 64 * 8 * 64) / 256, 256, 0, stream>>>(cb, packed);
    cnorm_kernel<<<(KK * CSZ) / 4, 256, 0, stream>>>(cb, cn_d, cn_f);
    rvq_kernel<<<NROWS / TM, NTHR, 0, stream>>>(z, cb, packed, cn_d, cn_f, out);
}

// Round 24
// 106.358 us; speedup vs baseline: 1.8382x; 1.8382x over previous
//
#include <hip/hip_runtime.h>
#include <hip/hip_bf16.h>

#define DD 256
#define KK 4
#define CSZ 1024
#define NROWS 16384
#define TM 16           // rows per block -> 1024 blocks, 3-4 per CU
#define NTHR 256        // 4 waves; wave wv scans tiles [wv*16, wv*16+16)
#define TAU 0.5f
#define MAXC 128

typedef __attribute__((ext_vector_type(8))) short bf16x8;
typedef __attribute__((ext_vector_type(4))) float f32x4;

__device__ __forceinline__ short f2bf(float f) {
    __hip_bfloat16 h = __float2bfloat16(f);
    return (short)__builtin_bit_cast(unsigned short, h);
}
__device__ __forceinline__ float bf2f(short s) {
    unsigned u = ((unsigned)(unsigned short)s) << 16;
    return __builtin_bit_cast(float, u);
}
__device__ __forceinline__ unsigned long long enc_d(double d) {
    unsigned long long u = __double_as_longlong(d);
    return (u & 0x8000000000000000ull) ? ~u : (u | 0x8000000000000000ull);
}

// pack codebook into MFMA B-fragment order (one coalesced 1KB stream per load)
__global__ __launch_bounds__(256) void cb_pack(const float* __restrict__ cb,
                                               short* __restrict__ packed) {
    int idx  = blockIdx.x * 256 + threadIdx.x;       // over 4*64*8*64 = 131072
    int lane = idx & 63;
    int kk   = (idx >> 6) & 7;
    int tg   = idx >> 9;                             // k*64 + tile
    int k    = tg >> 6;
    int ctg  = tg & 63;
    int c    = ctg * 16 + (lane & 15);
    int d0   = kk * 32 + (lane >> 4) * 8;
    const float* src = cb + ((size_t)(k * CSZ + c)) * DD + d0;
    short* dst = packed + (size_t)idx * 8;
#pragma unroll
    for (int j = 0; j < 8; ++j) dst[j] = f2bf(src[j]);
}

// per-entry squared norms, wave-per-entry (coalesced)
__global__ __launch_bounds__(256) void cnorm_kernel(const float* __restrict__ cb,
                                                    double* __restrict__ cn_d,
                                                    float* __restrict__ cn_f) {
    int wv = threadIdx.x >> 6, l = threadIdx.x & 63;
    int e = blockIdx.x * 4 + wv;                     // grid 1024 -> 4096 entries
    float4 v = *(const float4*)(cb + (size_t)e * DD + l * 4);
    double s = (double)v.x * (double)v.x + (double)v.y * (double)v.y
             + (double)v.z * (double)v.z + (double)v.w * (double)v.w;
#pragma unroll
    for (int off = 32; off > 0; off >>= 1) s += __shfl_xor(s, off, 64);
    if (l == 0) { cn_d[e] = s; cn_f[e] = (float)s; }
}

// coalesced fragment load from packed codebook; t_ is the GLOBAL tile id (0..63)
#define LOADB(Bv, CNv, t_) {                                          \
    const short* bp_ = pkk + (size_t)(t_) * 4096 + l * 8;             \
    _Pragma("unroll")                                                 \
    for (int kk = 0; kk < 8; ++kk)                                    \
        Bv[kk] = *(const bf16x8*)(bp_ + kk * 512);                    \
    CNv = cnfk[(t_) * 16 + l15]; }

// positive-float keys: dist > 0 here, so raw f32 bits compare as unsigned.
#define KUPD(dval) {                                                  \
    float dc_ = fmaxf((dval), 0.f);                                   \
    unsigned kx_ = (__builtin_bit_cast(unsigned, dc_) & 0xFFFFFC00u)  \
                   | (unsigned)cE_;                                   \
    unsigned mx_ = (b0[reg] > kx_) ? b0[reg] : kx_;                   \
    b0[reg] = (b0[reg] < kx_) ? b0[reg] : kx_;                        \
    b1[reg] = (b1[reg] < mx_) ? b1[reg] : mx_; }

#define TILE1(Bv, CNv, t_) {                                          \
    f32x4 ac = {0.f,0.f,0.f,0.f};                                     \
    _Pragma("unroll")                                                 \
    for (int kk = 0; kk < 8; ++kk)                                    \
        ac = __builtin_amdgcn_mfma_f32_16x16x32_bf16(A[kk], Bv[kk], ac, 0,0,0); \
    const int cE_ = (t_) * 16 + l15;                                  \
    _Pragma("unroll")                                                 \
    for (int reg = 0; reg < 4; ++reg) {                               \
        KUPD(fmaf(-2.f, ac[reg], CNv));                               \
    } }

__global__ __launch_bounds__(NTHR) void rvq_kernel(const float* __restrict__ z,
                                                  const float* __restrict__ cb,
                                                  const short* __restrict__ packed,
                                                  const double* __restrict__ cn_d,
                                                  const float* __restrict__ cn_f,
                                                  float* __restrict__ out) {
    // transposed double-compensated residual: fp32 hi + bf16 lo
    __shared__ float res_hi[DD][TM + 1];             // 17,408 B  (2-way banks max)
    __shared__ short res_lo[DD][TM + 2];             // 9,216 B
    __shared__ unsigned wrowmin[4][TM];
    __shared__ int cand[MAXC];
    __shared__ unsigned long long rowkey[2][TM];
    __shared__ int ncand;

    const int tid = threadIdx.x;                     // 0..255
    const int l   = tid & 63;        // lane
    const int wv  = tid >> 6;        // wave 0..3
    const int l15 = l & 15;
    const int q   = l >> 4;          // quarter 0..3
    const int q8  = q * 8;
    const int row0 = blockIdx.x * TM;

    // ---- init: hi = z (exact, transposed), lo = 0; rowkey/ncand ----
#pragma unroll 4
    for (int r = 0; r < TM; ++r) {
        res_hi[tid][r] = z[(size_t)(row0 + r) * DD + tid];
        res_lo[tid][r] = 0;
    }
    if (tid < TM) { rowkey[0][tid] = ~0ull; rowkey[1][tid] = ~0ull; }
    if (tid == 0) ncand = 0;
    __syncthreads();

    for (int k = 0; k < KK; ++k) {
        const int kb = k & 1;
        // ---- A fragments (row = l15, d = kk*32 + q8 + j), scalar LDS reads ----
        bf16x8 A[8];
#pragma unroll
        for (int kk = 0; kk < 8; ++kk) {
            bf16x8 a;
#pragma unroll
            for (int j = 0; j < 8; ++j)
                a[j] = f2bf(res_hi[kk * 32 + q8 + j][l15]);
            A[kk] = a;
        }

        // ---- MFMA scan over this wave's 16 tiles (single-buffered; TLP hides) ----
        const short* __restrict__ pkk  = packed + (size_t)k * CSZ * DD;
        const float* __restrict__ cnfk = cn_f + k * CSZ;
        unsigned b0[4], b1[4];
#pragma unroll
        for (int reg = 0; reg < 4; ++reg) { b0[reg] = ~0u; b1[reg] = ~0u; }

        {
            bf16x8 Bx[8];
            float cnX;
#pragma unroll 1
            for (int t = wv * 16; t < wv * 16 + 16; ++t) {
                LOADB(Bx, cnX, t);
                TILE1(Bx, cnX, t);
            }
        }

        // ---- per-wave row mins (16-lane groups) ----
#pragma unroll
        for (int reg = 0; reg < 4; ++reg) {
            unsigned m = b0[reg];
            m = min(m, (unsigned)__shfl_xor((int)m, 1, 64));
            m = min(m, (unsigned)__shfl_xor((int)m, 2, 64));
            m = min(m, (unsigned)__shfl_xor((int)m, 4, 64));
            m = min(m, (unsigned)__shfl_xor((int)m, 8, 64));
            if (l15 == 0) wrowmin[wv][q * 4 + reg] = m;
        }
        __syncthreads();                                   // B1

        // ---- capture: block min over 4 waves; best+2nd within TAU ----
#pragma unroll
        for (int reg = 0; reg < 4; ++reg) {
            const int row = q * 4 + reg;
            unsigned rk = min(min(wrowmin[0][row], wrowmin[1][row]),
                              min(wrowmin[2][row], wrowmin[3][row]));
            float thrf = __builtin_bit_cast(float, rk | 0x3FFu) + TAU;
            unsigned tkey = (__builtin_bit_cast(unsigned, thrf) & 0xFFFFFC00u) | 0x3FFu;
            if (b0[reg] <= tkey) {
                int sl = atomicAdd(&ncand, 1);
                if (sl < MAXC) cand[sl] = row | ((int)(b0[reg] & 0x3FFu) << 16);
            }
            if (b1[reg] <= tkey) {
                int sl = atomicAdd(&ncand, 1);
                if (sl < MAXC) cand[sl] = row | ((int)(b1[reg] & 0x3FFu) << 16);
            }
        }
        __syncthreads();                                   // B2

        // ---- fp64 refine on hi+lo: 16 16-lane groups, strided ----
        const int nc = (ncand < MAXC) ? ncand : MAXC;
        const float* __restrict__ cbk   = cb + (size_t)k * CSZ * DD;
        const double* __restrict__ cndk = cn_d + k * CSZ;
        const int g = tid >> 4;                            // group 0..15
        for (int i = g; i < nc; i += 16) {
            int rc  = cand[i];
            int row = rc & 0xFFFF;
            int c   = rc >> 16;
            const float* crow = cbk + (size_t)c * DD;
            double p = 0.0;
#pragma unroll
            for (int ii = 0; ii < 16; ++ii) {
                int d = ii * 16 + l15;
                double rv = (double)res_hi[d][row] + (double)bf2f(res_lo[d][row]);
                p += rv * (double)crow[d];
            }
            p += __shfl_xor(p, 1, 64);
            p += __shfl_xor(p, 2, 64);
            p += __shfl_xor(p, 4, 64);
            p += __shfl_xor(p, 8, 64);
            if (l15 == 0) {
                double dist = cndk[c] - 2.0 * p;
                unsigned long long key =
                    (enc_d(dist) & 0xFFFFFFFFFFFFFC00ull) | (unsigned long long)c;
                atomicMin(&rowkey[kb][row], key);
            }
        }
        __syncthreads();                                   // B3

        // ---- idx write (direct, f32) + residual update + resets ----
        if (tid < TM)
            out[(size_t)NROWS * DD + (size_t)(row0 + tid) * KK + k] =
                (float)(int)(rowkey[kb][tid] & 1023ull);
#pragma unroll 4
        for (int r = 0; r < TM; ++r) {
            int c = (int)(rowkey[kb][r] & 1023ull);        // broadcast LDS read
            double qv = (double)cbk[(size_t)c * DD + tid];
            double rd = (double)res_hi[tid][r] + (double)bf2f(res_lo[tid][r]);
            double s  = qv - rd;       // stop_gradient(q - residual)
            double zq = rd + s;        // z_q value
            double rn = rd - zq;       // next residual
            float hi = (float)rn;
            res_hi[tid][r] = hi;
            res_lo[tid][r] = f2bf((float)(rn - (double)hi));
        }
        if (tid < TM) rowkey[kb ^ 1][tid] = ~0ull;
        if (tid == 0) ncand = 0;
        __syncthreads();                                   // B4
    }

    // ---- z_q_final = z - residual_final (f32 out, chunk 0) ----
#pragma unroll 4
    for (int r = 0; r < TM; ++r) {
        size_t o = (size_t)(row0 + r) * DD + tid;
        double rv = (double)res_hi[tid][r] + (double)bf2f(res_lo[tid][r]);
        out[o] = (float)((double)z[o] - rv);
    }
}

extern "C" void kernel_launch(void* const* d_in, const int* in_sizes, int n_in,
                              void* d_out, int out_size, void* d_ws, size_t ws_size,
                              hipStream_t stream) {
    (void)in_sizes; (void)n_in; (void)out_size; (void)ws_size;
    const float* z  = (const float*)d_in[0];
    const float* cb = (const float*)d_in[1];

    char* ws = (char*)d_ws;
    short*  packed = (short*)ws;                                  // 2 MB
    double* cn_d  = (double*)(ws + (size_t)2 * 1024 * 1024);      // 32 KB
    float*  cn_f  = (float*)(ws + (size_t)2 * 1024 * 1024 + 32 * 1024);  // 16 KB
    float* out = (float*)d_out;

    cb_pack<<<(KK * 64 * 8 * 64) / 256, 256, 0, stream>>>(cb, packed);
    cnorm_kernel<<<(KK * CSZ) / 4, 256, 0, stream>>>(cb, cn_d, cn_f);
    rvq_kernel<<<NROWS / TM, NTHR, 0, stream>>>(z, cb, packed, cn_d, cn_f, out);
}